// Round 4
// baseline (839.635 us; speedup 1.0000x reference)
//
#include <hip/hip_runtime.h>

#define MROWS 8192
#define NCOLS 128

using f32x4  = __attribute__((ext_vector_type(4))) float;
using bf16x8 = __attribute__((ext_vector_type(8))) short;
using u32x4  = __attribute__((ext_vector_type(4))) unsigned int;
using u32x2  = __attribute__((ext_vector_type(2))) unsigned int;

__device__ __forceinline__ unsigned short f2bf(float f) {
    unsigned int u = __float_as_uint(f);
    u += 0x7fffu + ((u >> 16) & 1u);   // RNE
    return (unsigned short)(u >> 16);
}
__device__ __forceinline__ unsigned int pk2(float a, float b) {
    return (unsigned int)f2bf(a) | ((unsigned int)f2bf(b) << 16);
}
__device__ __forceinline__ bf16x8 cvt8(f32x4 lo, f32x4 hi) {
    union { u32x4 u; bf16x8 h; } r;
    r.u.x = pk2(lo.x, lo.y); r.u.y = pk2(lo.z, lo.w);
    r.u.z = pk2(hi.x, hi.y); r.u.w = pk2(hi.z, hi.w);
    return r.h;
}
__device__ __forceinline__ bf16x8 asbf(u32x4 v) {
    union { u32x4 u; bf16x8 h; } r; r.u = v; return r.h;
}

// Register staging buffer for one 64-wide K-step (per lane):
//   a[kk][half] : A fp32 fragments (row lrow, 32B per kk)
//   b[nt][kk]   : B bf16 fragments (col base + nt*16 + lrow)
struct Buf {
    f32x4 a[2][2];
    u32x4 b[2][2];
};

// C[M,128] = A[M,K](fp32) @ B[K,128], B stored transposed bf16 Bt[c][k], row stride ldb.
// NO LDS, NO BARRIERS. Wave tile 16r x 32c; block = 4 waves (2m x 2n) = 32r x 64c.
// Grid 512 (2 blocks/CU, 8 waves/CU). A fragments loaded global->reg (fp32, dense 64B
// sectors: 4 lanes/row cover 64B contiguous), converted to bf16 in-register. B fragments
// loaded straight from L2 (Bt is 2MB, XCD-L2-resident). 4 named register buffers at
// prefetch distance 2: without barriers the compiler emits counted vmcnt -> the global
// pipe never drains (the round-2 killer was vmcnt(0) before every s_barrier).
// XCD swizzle: both n-halves of an m-stripe land on the same XCD so each A row is
// fetched from HBM once and served to its sibling from L2.
// OUTMODE 0: bf16 transposed out[c][r];  1: same * filt[r];  2: fp32 row-major out[r][c].
template <int OUTMODE>
__global__ __launch_bounds__(256) void gemm_stream(
    const float* __restrict__ A,
    const unsigned short* __restrict__ Bt,
    void* __restrict__ out,
    const float* __restrict__ filt,
    int Kdim, int ldb)
{
    const int tid  = threadIdx.x;
    const int lane = tid & 63;
    const int wv   = tid >> 6;            // 0..3
    const int wm   = (wv >> 1) * 16;      // 0 / 16
    const int wn   = (wv & 1) * 32;       // 0 / 32
    const int lrow = lane & 15;
    const int lq   = lane >> 4;

    // XCD-aware decode: 512 blocks = 8 XCDs x 64 slots; each XCD owns 32 m-tiles x 2 n-halves.
    const int bid   = blockIdx.x;
    const int xcd   = bid & 7;
    const int slot  = bid >> 3;
    const int mtile = xcd * 32 + (slot >> 1);   // 0..255
    const int nhalf = slot & 1;                 // 0..1

    const int mbase = mtile * 32 + wm;          // wave's A-row base
    const int cbase = nhalf * 64 + wn;          // wave's B-col base

    const float*          Ap  = A  + (size_t)(mbase + lrow) * Kdim + lq * 8;
    const unsigned short* Bp0 = Bt + (size_t)(cbase + lrow) * ldb + lq * 8;
    const unsigned short* Bp1 = Bp0 + (size_t)16 * ldb;

    f32x4 acc0 = {0.f, 0.f, 0.f, 0.f};
    f32x4 acc1 = {0.f, 0.f, 0.f, 0.f};

    Buf s0, s1, s2, s3;

#define LOADB(B, ks) do { \
        B.a[0][0] = *(const f32x4*)(Ap + (ks));          \
        B.a[0][1] = *(const f32x4*)(Ap + (ks) + 4);      \
        B.a[1][0] = *(const f32x4*)(Ap + (ks) + 32);     \
        B.a[1][1] = *(const f32x4*)(Ap + (ks) + 36);     \
        B.b[0][0] = *(const u32x4*)(Bp0 + (ks));         \
        B.b[0][1] = *(const u32x4*)(Bp0 + (ks) + 32);    \
        B.b[1][0] = *(const u32x4*)(Bp1 + (ks));         \
        B.b[1][1] = *(const u32x4*)(Bp1 + (ks) + 32);    \
    } while (0)

#define COMP(B) do { \
        bf16x8 af0 = cvt8(B.a[0][0], B.a[0][1]);                                   \
        acc0 = __builtin_amdgcn_mfma_f32_16x16x32_bf16(af0, asbf(B.b[0][0]), acc0, 0, 0, 0); \
        acc1 = __builtin_amdgcn_mfma_f32_16x16x32_bf16(af0, asbf(B.b[1][0]), acc1, 0, 0, 0); \
        bf16x8 af1 = cvt8(B.a[1][0], B.a[1][1]);                                   \
        acc0 = __builtin_amdgcn_mfma_f32_16x16x32_bf16(af1, asbf(B.b[0][1]), acc0, 0, 0, 0); \
        acc1 = __builtin_amdgcn_mfma_f32_16x16x32_bf16(af1, asbf(B.b[1][1]), acc1, 0, 0, 0); \
    } while (0)

    const int iters = Kdim >> 6;     // K/64: 128 (big GEMMs) or 4 (GEMM1) — divisible by 4
    LOADB(s0, 0);
    LOADB(s1, 64);
    for (int it = 0; it < iters; it += 4) {
        const int ks = it * 64;
        if (it + 2 < iters) LOADB(s2, ks + 128);      // it+2
        COMP(s0);                                     // step it
        if (it + 3 < iters) LOADB(s3, ks + 192);      // it+3
        COMP(s1);                                     // step it+1
        if (it + 4 < iters) LOADB(s0, ks + 256);      // it+4
        COMP(s2);                                     // step it+2
        if (it + 5 < iters) LOADB(s1, ks + 320);      // it+5
        COMP(s3);                                     // step it+3
    }
#undef LOADB
#undef COMP

    const int r = mbase + lq * 4;
    if (OUTMODE == 2) {
        float* O = (float*)out;
#pragma unroll
        for (int nt = 0; nt < 2; ++nt) {
            const int c = cbase + nt * 16 + lrow;
            const f32x4 v = nt ? acc1 : acc0;
#pragma unroll
            for (int e = 0; e < 4; ++e)
                O[(size_t)(r + e) * NCOLS + c] = v[e];
        }
    } else {
        unsigned short* O = (unsigned short*)out;
        f32x4 v0 = acc0, v1 = acc1;
        if (OUTMODE == 1) {
            const f32x4 fl = *(const f32x4*)&filt[r];   // r is a multiple of 4 -> 16B aligned
            v0 *= fl;
            v1 *= fl;
        }
        u32x2 o;
        o.x = pk2(v0.x, v0.y); o.y = pk2(v0.z, v0.w);
        *(u32x2*)&O[(size_t)(cbase + lrow) * MROWS + r] = o;
        o.x = pk2(v1.x, v1.y); o.y = pk2(v1.z, v1.w);
        *(u32x2*)&O[(size_t)(cbase + 16 + lrow) * MROWS + r] = o;
    }
}

// Wt[c][k] = bf16(W[k][c]) : 256x128 fp32 -> transposed bf16
__global__ void convert_w(const float* __restrict__ W, unsigned short* __restrict__ Wt) {
    int idx = blockIdx.x * 256 + threadIdx.x;   // 32768 total
    int k = idx >> 7, c = idx & 127;
    Wt[c * 256 + k] = f2bf(W[idx]);
}

extern "C" void kernel_launch(void* const* d_in, const int* in_sizes, int n_in,
                              void* d_out, int out_size, void* d_ws, size_t ws_size,
                              hipStream_t stream) {
    const float* features     = (const float*)d_in[0];
    const float* wavelets     = (const float*)d_in[1];
    const float* wavelets_inv = (const float*)d_in[2];
    const float* W            = (const float*)d_in[3];
    const float* filt         = (const float*)d_in[4];
    float* outp = (float*)d_out;

    char* ws = (char*)d_ws;
    unsigned short* Tt = (unsigned short*)ws;                              // 2 MB  Tt[c][r]
    unsigned short* Rt = (unsigned short*)(ws + (size_t)2 * 1024 * 1024);  // 2 MB  Rt[c][r]
    unsigned short* Wt = (unsigned short*)(ws + (size_t)4 * 1024 * 1024);  // 64 KB Wt[c][k]

    // 1) W -> Wt (bf16, transposed)
    convert_w<<<128, 256, 0, stream>>>(W, Wt);
    // 2) Tt = (features @ W)^T            (K=256)
    gemm_stream<0><<<512, 256, 0, stream>>>(features,     Wt, (void*)Tt,   nullptr, 256,  256);
    // 3) Rt = (filt ⊙ (wavelets_inv @ T))^T   (K=8192, filt fused)
    gemm_stream<1><<<512, 256, 0, stream>>>(wavelets_inv, Tt, (void*)Rt,   filt,    8192, 8192);
    // 4) out = wavelets @ R               (K=8192, fp32 row-major)
    gemm_stream<2><<<512, 256, 0, stream>>>(wavelets,     Rt, (void*)outp, nullptr, 8192, 8192);
}